// Round 6
// baseline (138.465 us; speedup 1.0000x reference)
//
#include <hip/hip_runtime.h>
#include <math.h>

#define NSAMP 131072

typedef _Float16 half8v __attribute__((ext_vector_type(8)));
typedef float    f32x4  __attribute__((ext_vector_type(4)));

__device__ __forceinline__ float fast_tanh(float x) {
    // valid for all x: exp2 saturates to 0/inf, rcp gives exact +-1 limits
    float e = __builtin_amdgcn_exp2f(x * 2.885390081777927f); // exp(2x)
    return fmaf(-2.0f, __builtin_amdgcn_rcpf(e + 1.0f), 1.0f);
}

__global__ __launch_bounds__(256, 3)
void cnf_logp_kernel(const float* __restrict__ xin, const float* __restrict__ tin,
                     const float* __restrict__ W1, const float* __restrict__ b1,
                     const float* __restrict__ W2, const float* __restrict__ b2,
                     const float* __restrict__ W3, const float* __restrict__ b3,
                     const float* __restrict__ vol, float* __restrict__ out)
{
    const int tid  = threadIdx.x;
    const int lane = tid & 63;
    const int col  = lane & 15;   // sample slot (B/C column); A-row for weight frags
    const int g    = lane >> 4;   // lane group

    // slot k-map shared by ALL frags (hw-map mismatches cancel):
    //   k(e,g) = 4g + (e&3) + 16*(e>>2); e>=4 -> slot >= 16

    // ---------------- layer-1 MFMA A-frags (static) ----------------
    // pre[k,s] = sum over slots: 0-3 W1hi*zhi, 4-7 W1lo*zhi, 8-11 W1hi*zlo,
    //            12 b1hi*1, 13 b1lo*1  (exact to ~2^-22)
    half8v A1[4];   // [kq], rows = k within quarter (= col)
    #pragma unroll
    for (int kq = 0; kq < 4; ++kq) {
        half8v a;
        #pragma unroll
        for (int e = 0; e < 8; ++e) a[e] = (_Float16)0.0f;
        const int krow = kq*16 + col;
        #pragma unroll
        for (int e = 0; e < 4; ++e) {
            const float w = W1[e*64 + krow];
            const _Float16 whi = (_Float16)w;
            const _Float16 wlo = (_Float16)(w - (float)whi);
            _Float16 v = (_Float16)0.0f;
            if (g == 0 || g == 2)      v = whi;
            else if (g == 1)           v = wlo;
            else {                     // g == 3: bias slots 12/13
                const float bv = b1[krow];
                const _Float16 bhi = (_Float16)bv;
                if (e == 0)      v = bhi;
                else if (e == 1) v = (_Float16)(bv - (float)bhi);
            }
            a[e] = v;
        }
        A1[kq] = a;
    }

    // ---------------- layer-2 weight A-frags (rows = j) ----------------
    half8v AW2[8];   // [nt*2+kh] : A[j = nt*16+col, k] = W2[k, j]
    half8v AHW[8];   // H[k,j] = W2[k,j] * sum_i W1[i,k] W3[j,i]
    #pragma unroll
    for (int nt = 0; nt < 4; ++nt) {
        const int j = nt*16 + col;
        const float w3j0 = W3[j*3+0], w3j1 = W3[j*3+1], w3j2 = W3[j*3+2];
        #pragma unroll
        for (int kh = 0; kh < 2; ++kh) {
            #pragma unroll
            for (int e = 0; e < 8; ++e) {
                const int k = kh*32 + 4*g + (e & 3) + 16*(e >> 2);
                const float w2v = W2[k*64 + j];
                const float gv  = W1[0*64+k]*w3j0 + W1[1*64+k]*w3j1 + W1[2*64+k]*w3j2;
                AW2[nt*2 + kh][e] = (_Float16)w2v;
                AHW[nt*2 + kh][e] = (_Float16)(w2v * gv);
            }
        }
    }
    // b2 in OUTPUT-j indexing: j_out = nt*16 + 4g + r
    f32x4 b2v[4];
    #pragma unroll
    for (int nt = 0; nt < 4; ++nt) {
        #pragma unroll
        for (int r = 0; r < 4; ++r) b2v[nt][r] = b2[nt*16 + 4*g + r];
    }
    // W3 A-frags for the f-MFMA: rows = channel (col<3), K = j
    half8v A3[2];
    #pragma unroll
    for (int kp = 0; kp < 2; ++kp) {
        #pragma unroll
        for (int e = 0; e < 8; ++e) {
            const int j = kp*32 + 4*g + (e & 3) + 16*(e >> 2);
            A3[kp][e] = (col < 3) ? (_Float16)W3[j*3 + col] : (_Float16)0.0f;
        }
    }
    const float b3c0 = b3[0], b3c1 = b3[1], b3c2 = b3[2];

    // ---------------- per-sample state (sample = col, replicated x4 groups) ----------------
    const int idx = blockIdx.x*64 + (tid >> 6)*16 + col;
    const float x0v = xin[idx*3 + 0], x1v = xin[idx*3 + 1], x2v = xin[idx*3 + 2];
    const float t0  = tin[idx];

    float z0 = x0v, z1 = x1v, z2 = x2v;
    float dacc = 0.0f;
    const float hstep = 0.25f;
    float kz0 = 0.f, kz1 = 0.f, kz2 = 0.f;
    float sa0 = 0.f, sa1 = 0.f, sa2 = 0.f;

    const bool g2f = (g == 2), g3f = (g == 3);

    #pragma unroll 4
    for (int it = 0; it < 16; ++it) {
        const int st   = it & 3;              // compile-time after unroll-4
        const int step = it >> 2;
        const float alpha = (st == 0) ? 0.0f : ((st == 3) ? hstep : 0.5f * hstep);
        const float wgt   = (st == 1 || st == 2) ? (hstep * (1.0f/3.0f)) : (hstep * (1.0f/6.0f));
        const float s     = (float)step * hstep + alpha;
        const float zi0 = fmaf(alpha, kz0, z0);
        const float zi1 = fmaf(alpha, kz1, z1);
        const float zi2 = fmaf(alpha, kz2, z2);
        const float tt  = t0 * (1.0f - s);

        // ---- layer 1 via MFMA: B-frag carries [zhi | zhi | zlo | 1] by group ----
        const _Float16 z0h = (_Float16)zi0, z1h = (_Float16)zi1,
                       z2h = (_Float16)zi2, tth = (_Float16)tt;
        const _Float16 z0l = (_Float16)(zi0 - (float)z0h);
        const _Float16 z1l = (_Float16)(zi1 - (float)z1h);
        const _Float16 z2l = (_Float16)(zi2 - (float)z2h);
        const _Float16 ttl = (_Float16)(tt  - (float)tth);
        half8v B1;
        #pragma unroll
        for (int e = 0; e < 8; ++e) B1[e] = (_Float16)0.0f;
        B1[0] = g3f ? (_Float16)1.0f : (g2f ? z0l : z0h);
        B1[1] = g3f ? (_Float16)1.0f : (g2f ? z1l : z1h);
        B1[2] = g3f ? (_Float16)0.0f : (g2f ? z2l : z2h);
        B1[3] = g3f ? (_Float16)0.0f : (g2f ? ttl : tth);

        float h[4][4];   // h[kq][r], k = kq*16 + 4g + r, sample = col
        #pragma unroll
        for (int kq = 0; kq < 4; ++kq) {
            f32x4 z4; z4[0]=0.f; z4[1]=0.f; z4[2]=0.f; z4[3]=0.f;
            z4 = __builtin_amdgcn_mfma_f32_16x16x32_f16(A1[kq], B1, z4, 0, 0, 0);
            #pragma unroll
            for (int r = 0; r < 4; ++r) h[kq][r] = fast_tanh(z4[r]);
        }

        // ---- pack h -> layer-2 B-frags (pure per-lane repack) ----
        half8v BH[2], BQ[2];
        half8v hone;
        #pragma unroll
        for (int e = 0; e < 8; ++e) hone[e] = (_Float16)1.0f;
        #pragma unroll
        for (int kh = 0; kh < 2; ++kh) {
            #pragma unroll
            for (int e = 0; e < 8; ++e)
                BH[kh][e] = (_Float16)h[kh*2 + (e >> 2)][e & 3];
            BQ[kh] = hone - BH[kh]*BH[kh];   // s1 = 1 - h^2 (packed)
        }

        // ---- layer 2 + divergence bilinear: d2 = cs - old_d2 directly ----
        f32x4 a2[4], d2[4];
        #pragma unroll
        for (int nt = 0; nt < 4; ++nt) {
            f32x4 acc = b2v[nt];
            acc = __builtin_amdgcn_mfma_f32_16x16x32_f16(AW2[nt*2+0], BH[0], acc, 0, 0, 0);
            acc = __builtin_amdgcn_mfma_f32_16x16x32_f16(AW2[nt*2+1], BH[1], acc, 0, 0, 0);
            a2[nt] = acc;
            f32x4 z4; z4[0]=0.f; z4[1]=0.f; z4[2]=0.f; z4[3]=0.f;
            z4  = __builtin_amdgcn_mfma_f32_16x16x32_f16(AHW[nt*2+0], BQ[0], z4, 0, 0, 0);
            z4  = __builtin_amdgcn_mfma_f32_16x16x32_f16(AHW[nt*2+1], BQ[1], z4, 0, 0, 0);
            d2[nt] = z4;
        }

        // ---- epilogue: per-lane j-slice (j = nt*16 + 4g + r), sample = col ----
        float h2v[4][4];
        float pdv = 0.0f;
        #pragma unroll
        for (int nt = 0; nt < 4; ++nt) {
            #pragma unroll
            for (int r = 0; r < 4; ++r) {
                const float h2 = fast_tanh(a2[nt][r]);
                h2v[nt][r] = h2;
                const float s2 = fmaf(-h2, h2, 1.0f);
                pdv = fmaf(s2, d2[nt][r], pdv);
            }
        }
        // f = h2 @ W3 via 2nd-level MFMA: tanh(a2) repacks as K=j B-frag
        half8v B2h[2];
        #pragma unroll
        for (int kp = 0; kp < 2; ++kp) {
            #pragma unroll
            for (int e = 0; e < 8; ++e)
                B2h[kp][e] = (_Float16)h2v[kp*2 + (e >> 2)][e & 3];
        }
        f32x4 fD; fD[0]=0.f; fD[1]=0.f; fD[2]=0.f; fD[3]=0.f;
        fD = __builtin_amdgcn_mfma_f32_16x16x32_f16(A3[0], B2h[0], fD, 0, 0, 0);
        fD = __builtin_amdgcn_mfma_f32_16x16x32_f16(A3[1], B2h[1], fD, 0, 0, 0);

        // dv: sum over 4 groups; f: rows 0..2 live in group-0 lanes
        pdv += __shfl_xor(pdv, 16);
        pdv += __shfl_xor(pdv, 32);
        const float f0 = __shfl(fD[0], col) + b3c0;
        const float f1 = __shfl(fD[1], col) + b3c1;
        const float f2 = __shfl(fD[2], col) + b3c2;

        // ---- RK4 stage update (sample = col, replicated across groups) ----
        const float v0 = -t0 * f0, v1 = -t0 * f1, v2 = -t0 * f2;
        const float vd =  t0 * pdv;
        kz0 = v0; kz1 = v1; kz2 = v2;
        dacc = fmaf(wgt, vd, dacc);
        if (st == 0) { sa0 = wgt*v0; sa1 = wgt*v1; sa2 = wgt*v2; }
        else         { sa0 = fmaf(wgt, v0, sa0); sa1 = fmaf(wgt, v1, sa1); sa2 = fmaf(wgt, v2, sa2); }
        if (st == 3) { z0 += sa0; z1 += sa1; z2 += sa2; }
    }

    // ---------------- mask, grid-sample, store (group 0 only) ----------------
    if (g == 0) {
        const bool m = (t0 > 0.0f);
        const float q0 = m ? z0 : x0v;
        const float q1 = m ? z1 : x1v;
        const float q2 = m ? z2 : x2v;
        const float dfin = m ? dacc : 0.0f;

        const float px = ((q0 * 0.2f + 1.0f) * 100.0f - 1.0f) * 0.5f;
        const float py = ((q1 * 0.2f + 1.0f) * 100.0f - 1.0f) * 0.5f;
        const float pz = ((q2 * 0.2f + 1.0f) * 100.0f - 1.0f) * 0.5f;
        const float fx = floorf(px), fy = floorf(py), fz = floorf(pz);
        const int ix0 = (int)fx, iy0 = (int)fy, iz0 = (int)fz;
        const float wx1 = px - fx, wy1 = py - fy, wz1 = pz - fz;

        float gs = 0.0f;
        #pragma unroll
        for (int c = 0; c < 8; ++c) {
            const int dxc = c & 1, dyc = (c >> 1) & 1, dzc = (c >> 2) & 1;
            const int ix = ix0 + dxc, iy = iy0 + dyc, iz = iz0 + dzc;
            const float w = (dxc ? wx1 : 1.0f - wx1)
                          * (dyc ? wy1 : 1.0f - wy1)
                          * (dzc ? wz1 : 1.0f - wz1);
            if (ix >= 0 && ix < 100 && iy >= 0 && iy < 100 && iz >= 0 && iz < 100)
                gs += vol[(iz * 100 + iy) * 100 + ix] * w;
        }
        out[idx] = gs - dfin;
    }
}

extern "C" void kernel_launch(void* const* d_in, const int* in_sizes, int n_in,
                              void* d_out, int out_size, void* d_ws, size_t ws_size,
                              hipStream_t stream) {
    const float* x    = (const float*)d_in[0];
    const float* t    = (const float*)d_in[1];
    const float* W1   = (const float*)d_in[2];
    const float* b1   = (const float*)d_in[3];
    const float* W2   = (const float*)d_in[4];
    const float* b2   = (const float*)d_in[5];
    const float* W3   = (const float*)d_in[6];
    const float* b3   = (const float*)d_in[7];
    const float* vol  = (const float*)d_in[8];
    float* out = (float*)d_out;

    dim3 grid(NSAMP / 64), block(256);   // 4 waves/block, 16 samples/wave
    cnf_logp_kernel<<<grid, block, 0, stream>>>(x, t, W1, b1, W2, b2, W3, b3, vol, out);
}

// Round 7
// 110.347 us; speedup vs baseline: 1.2548x; 1.2548x over previous
//
#include <hip/hip_runtime.h>
#include <math.h>

#define NSAMP 131072

typedef _Float16 half8v __attribute__((ext_vector_type(8)));
typedef float    f32x4  __attribute__((ext_vector_type(4)));

__device__ __forceinline__ float fast_tanh(float x) {
    // valid for all x: exp2 saturates to 0/inf, rcp gives exact +-1 limits
    float e = __builtin_amdgcn_exp2f(x * 2.885390081777927f); // exp(2x)
    return fmaf(-2.0f, __builtin_amdgcn_rcpf(e + 1.0f), 1.0f);
}

__global__ __launch_bounds__(256, 2)
void cnf_logp_kernel(const float* __restrict__ xin, const float* __restrict__ tin,
                     const float* __restrict__ W1, const float* __restrict__ b1,
                     const float* __restrict__ W2, const float* __restrict__ b2,
                     const float* __restrict__ W3, const float* __restrict__ b3,
                     const float* __restrict__ vol, float* __restrict__ out)
{
    const int tid  = threadIdx.x;
    const int lane = tid & 63;
    const int col  = lane & 15;   // sample slot (B/C column); A-row for weight frags
    const int g    = lane >> 4;   // lane group

    // slot k-map shared by ALL frags (hw-map mismatches cancel):
    //   k(e,g) = 4g + (e&3) + 16*(e>>2); e>=4 -> slot >= 16

    // ---------------- layer-1 MFMA A-frags (static) ----------------
    // pre[k,s] = sum over slots: 0-3 W1hi*zhi, 4-7 W1lo*zhi, 8-11 W1hi*zlo,
    //            12 b1hi*1, 13 b1lo*1  (exact to ~2^-22)
    half8v A1[4];   // [kq], rows = k within quarter (= col)
    #pragma unroll
    for (int kq = 0; kq < 4; ++kq) {
        half8v a;
        #pragma unroll
        for (int e = 0; e < 8; ++e) a[e] = (_Float16)0.0f;
        const int krow = kq*16 + col;
        #pragma unroll
        for (int e = 0; e < 4; ++e) {
            const float w = W1[e*64 + krow];
            const _Float16 whi = (_Float16)w;
            const _Float16 wlo = (_Float16)(w - (float)whi);
            _Float16 v = (_Float16)0.0f;
            if (g == 0 || g == 2)      v = whi;
            else if (g == 1)           v = wlo;
            else {                     // g == 3: bias slots 12/13
                const float bv = b1[krow];
                const _Float16 bhi = (_Float16)bv;
                if (e == 0)      v = bhi;
                else if (e == 1) v = (_Float16)(bv - (float)bhi);
            }
            a[e] = v;
        }
        A1[kq] = a;
    }

    // ---------------- layer-2 weight A-frags (rows = j) ----------------
    half8v AW2[8];   // [nt*2+kh] : A[j = nt*16+col, k] = W2[k, j]
    half8v AHW[8];   // H[k,j] = W2[k,j] * sum_i W1[i,k] W3[j,i]
    #pragma unroll
    for (int nt = 0; nt < 4; ++nt) {
        const int j = nt*16 + col;
        const float w3j0 = W3[j*3+0], w3j1 = W3[j*3+1], w3j2 = W3[j*3+2];
        #pragma unroll
        for (int kh = 0; kh < 2; ++kh) {
            #pragma unroll
            for (int e = 0; e < 8; ++e) {
                const int k = kh*32 + 4*g + (e & 3) + 16*(e >> 2);
                const float w2v = W2[k*64 + j];
                const float gv  = W1[0*64+k]*w3j0 + W1[1*64+k]*w3j1 + W1[2*64+k]*w3j2;
                AW2[nt*2 + kh][e] = (_Float16)w2v;
                AHW[nt*2 + kh][e] = (_Float16)(w2v * gv);
            }
        }
    }
    // b2 in OUTPUT-j indexing: j_out = nt*16 + 4g + r
    f32x4 b2v[4];
    #pragma unroll
    for (int nt = 0; nt < 4; ++nt) {
        #pragma unroll
        for (int r = 0; r < 4; ++r) b2v[nt][r] = b2[nt*16 + 4*g + r];
    }
    // W3 A-frags for the f-MFMA: rows = channel (col<3), K = j
    half8v A3[2];
    #pragma unroll
    for (int kp = 0; kp < 2; ++kp) {
        #pragma unroll
        for (int e = 0; e < 8; ++e) {
            const int j = kp*32 + 4*g + (e & 3) + 16*(e >> 2);
            A3[kp][e] = (col < 3) ? (_Float16)W3[j*3 + col] : (_Float16)0.0f;
        }
    }
    const float b3c0 = b3[0], b3c1 = b3[1], b3c2 = b3[2];

    // ---------------- per-sample state (sample = col, replicated x4 groups) ----------------
    const int idx = blockIdx.x*64 + (tid >> 6)*16 + col;
    const float x0v = xin[idx*3 + 0], x1v = xin[idx*3 + 1], x2v = xin[idx*3 + 2];
    const float t0  = tin[idx];

    float z0 = x0v, z1 = x1v, z2 = x2v;
    float dacc = 0.0f;
    const float hstep = 0.25f;
    float kz0 = 0.f, kz1 = 0.f, kz2 = 0.f;
    float sa0 = 0.f, sa1 = 0.f, sa2 = 0.f;

    const bool g2f = (g == 2), g3f = (g == 3);

    #pragma unroll 1
    for (int it = 0; it < 16; ++it) {
        const int st   = it & 3;
        const int step = it >> 2;
        const float alpha = (st == 0) ? 0.0f : ((st == 3) ? hstep : 0.5f * hstep);
        const float wgt   = (st == 1 || st == 2) ? (hstep * (1.0f/3.0f)) : (hstep * (1.0f/6.0f));
        const float s     = (float)step * hstep + alpha;
        const float zi0 = fmaf(alpha, kz0, z0);
        const float zi1 = fmaf(alpha, kz1, z1);
        const float zi2 = fmaf(alpha, kz2, z2);
        const float tt  = t0 * (1.0f - s);

        // ---- layer 1 via MFMA: B-frag carries [zhi | zhi | zlo | 1] by group ----
        const _Float16 z0h = (_Float16)zi0, z1h = (_Float16)zi1,
                       z2h = (_Float16)zi2, tth = (_Float16)tt;
        const _Float16 z0l = (_Float16)(zi0 - (float)z0h);
        const _Float16 z1l = (_Float16)(zi1 - (float)z1h);
        const _Float16 z2l = (_Float16)(zi2 - (float)z2h);
        const _Float16 ttl = (_Float16)(tt  - (float)tth);
        half8v B1;
        #pragma unroll
        for (int e = 0; e < 8; ++e) B1[e] = (_Float16)0.0f;
        B1[0] = g3f ? (_Float16)1.0f : (g2f ? z0l : z0h);
        B1[1] = g3f ? (_Float16)1.0f : (g2f ? z1l : z1h);
        B1[2] = g3f ? (_Float16)0.0f : (g2f ? z2l : z2h);
        B1[3] = g3f ? (_Float16)0.0f : (g2f ? ttl : tth);

        float h[4][4];   // h[kq][r], k = kq*16 + 4g + r, sample = col
        #pragma unroll
        for (int kq = 0; kq < 4; ++kq) {
            f32x4 z4; z4[0]=0.f; z4[1]=0.f; z4[2]=0.f; z4[3]=0.f;
            z4 = __builtin_amdgcn_mfma_f32_16x16x32_f16(A1[kq], B1, z4, 0, 0, 0);
            #pragma unroll
            for (int r = 0; r < 4; ++r) h[kq][r] = fast_tanh(z4[r]);
        }

        // ---- pack h -> layer-2 B-frags (pure per-lane repack) ----
        half8v BH[2], BQ[2];
        half8v hone;
        #pragma unroll
        for (int e = 0; e < 8; ++e) hone[e] = (_Float16)1.0f;
        #pragma unroll
        for (int kh = 0; kh < 2; ++kh) {
            #pragma unroll
            for (int e = 0; e < 8; ++e)
                BH[kh][e] = (_Float16)h[kh*2 + (e >> 2)][e & 3];
            BQ[kh] = hone - BH[kh]*BH[kh];   // s1 = 1 - h^2 (packed)
        }

        // ---- layer 2 + divergence bilinear (cs pre-folded: d2 = sum H*(1-h^2)) ----
        f32x4 a2[4], d2[4];
        #pragma unroll
        for (int nt = 0; nt < 4; ++nt) {
            f32x4 acc = b2v[nt];
            acc = __builtin_amdgcn_mfma_f32_16x16x32_f16(AW2[nt*2+0], BH[0], acc, 0, 0, 0);
            acc = __builtin_amdgcn_mfma_f32_16x16x32_f16(AW2[nt*2+1], BH[1], acc, 0, 0, 0);
            a2[nt] = acc;
            f32x4 z4; z4[0]=0.f; z4[1]=0.f; z4[2]=0.f; z4[3]=0.f;
            z4  = __builtin_amdgcn_mfma_f32_16x16x32_f16(AHW[nt*2+0], BQ[0], z4, 0, 0, 0);
            z4  = __builtin_amdgcn_mfma_f32_16x16x32_f16(AHW[nt*2+1], BQ[1], z4, 0, 0, 0);
            d2[nt] = z4;
        }

        // ---- epilogue: per-lane j-slice (j = nt*16 + 4g + r), sample = col ----
        float h2v[4][4];
        float pdv = 0.0f;
        #pragma unroll
        for (int nt = 0; nt < 4; ++nt) {
            #pragma unroll
            for (int r = 0; r < 4; ++r) {
                const float h2 = fast_tanh(a2[nt][r]);
                h2v[nt][r] = h2;
                const float s2 = fmaf(-h2, h2, 1.0f);
                pdv = fmaf(s2, d2[nt][r], pdv);
            }
        }
        // f = h2 @ W3 via 2nd-level MFMA: tanh(a2) repacks as K=j B-frag
        half8v B2h[2];
        #pragma unroll
        for (int kp = 0; kp < 2; ++kp) {
            #pragma unroll
            for (int e = 0; e < 8; ++e)
                B2h[kp][e] = (_Float16)h2v[kp*2 + (e >> 2)][e & 3];
        }
        f32x4 fD; fD[0]=0.f; fD[1]=0.f; fD[2]=0.f; fD[3]=0.f;
        fD = __builtin_amdgcn_mfma_f32_16x16x32_f16(A3[0], B2h[0], fD, 0, 0, 0);
        fD = __builtin_amdgcn_mfma_f32_16x16x32_f16(A3[1], B2h[1], fD, 0, 0, 0);

        // dv: sum over 4 groups; f: rows 0..2 live in group-0 lanes
        pdv += __shfl_xor(pdv, 16);
        pdv += __shfl_xor(pdv, 32);
        const float f0 = __shfl(fD[0], col) + b3c0;
        const float f1 = __shfl(fD[1], col) + b3c1;
        const float f2 = __shfl(fD[2], col) + b3c2;

        // ---- RK4 stage update (sample = col, replicated across groups) ----
        const float v0 = -t0 * f0, v1 = -t0 * f1, v2 = -t0 * f2;
        const float vd =  t0 * pdv;
        kz0 = v0; kz1 = v1; kz2 = v2;
        dacc = fmaf(wgt, vd, dacc);
        if (st == 0) { sa0 = wgt*v0; sa1 = wgt*v1; sa2 = wgt*v2; }
        else         { sa0 = fmaf(wgt, v0, sa0); sa1 = fmaf(wgt, v1, sa1); sa2 = fmaf(wgt, v2, sa2); }
        if (st == 3) { z0 += sa0; z1 += sa1; z2 += sa2; }
    }

    // ---------------- mask, grid-sample, store (group 0 only) ----------------
    if (g == 0) {
        const bool m = (t0 > 0.0f);
        const float q0 = m ? z0 : x0v;
        const float q1 = m ? z1 : x1v;
        const float q2 = m ? z2 : x2v;
        const float dfin = m ? dacc : 0.0f;

        const float px = ((q0 * 0.2f + 1.0f) * 100.0f - 1.0f) * 0.5f;
        const float py = ((q1 * 0.2f + 1.0f) * 100.0f - 1.0f) * 0.5f;
        const float pz = ((q2 * 0.2f + 1.0f) * 100.0f - 1.0f) * 0.5f;
        const float fx = floorf(px), fy = floorf(py), fz = floorf(pz);
        const int ix0 = (int)fx, iy0 = (int)fy, iz0 = (int)fz;
        const float wx1 = px - fx, wy1 = py - fy, wz1 = pz - fz;

        float gs = 0.0f;
        #pragma unroll
        for (int c = 0; c < 8; ++c) {
            const int dxc = c & 1, dyc = (c >> 1) & 1, dzc = (c >> 2) & 1;
            const int ix = ix0 + dxc, iy = iy0 + dyc, iz = iz0 + dzc;
            const float w = (dxc ? wx1 : 1.0f - wx1)
                          * (dyc ? wy1 : 1.0f - wy1)
                          * (dzc ? wz1 : 1.0f - wz1);
            if (ix >= 0 && ix < 100 && iy >= 0 && iy < 100 && iz >= 0 && iz < 100)
                gs += vol[(iz * 100 + iy) * 100 + ix] * w;
        }
        out[idx] = gs - dfin;
    }
}

extern "C" void kernel_launch(void* const* d_in, const int* in_sizes, int n_in,
                              void* d_out, int out_size, void* d_ws, size_t ws_size,
                              hipStream_t stream) {
    const float* x    = (const float*)d_in[0];
    const float* t    = (const float*)d_in[1];
    const float* W1   = (const float*)d_in[2];
    const float* b1   = (const float*)d_in[3];
    const float* W2   = (const float*)d_in[4];
    const float* b2   = (const float*)d_in[5];
    const float* W3   = (const float*)d_in[6];
    const float* b3   = (const float*)d_in[7];
    const float* vol  = (const float*)d_in[8];
    float* out = (float*)d_out;

    dim3 grid(NSAMP / 64), block(256);   // 4 waves/block, 16 samples/wave
    cnf_logp_kernel<<<grid, block, 0, stream>>>(x, t, W1, b1, W2, b2, W3, b3, vol, out);
}